// Round 7
// baseline (6999.858 us; speedup 1.0000x reference)
//
#include <hip/hip_runtime.h>

namespace {
constexpr int kB = 16, kT = 512, kIN = 16, kD = 128, kH = 256, kL = 136, kO = 32;
constexpr int kSteps = kT - 1;      // 511
constexpr int NBLK = 256;           // block k: z3 tile d = k>>1, l-half = k&1
constexpr int NTHR = 512;
constexpr int LH   = 68;
constexpr int NTILE = 5;            // z3 MFMA n-tiles (80 cols, 68 real)
constexpr int NMLP = 8;             // blocks 0..7 also run the MLP
// ---- LDS layout (bytes); regions time-aliased where noted ----
constexpr int OFF_W3L = 0;                  // fw3 frags [5][8][2][64][8]bf16  81920
constexpr int OFF_W2F = 81920;              // fw2 frags [2][8][2][64][8]bf16  32768
constexpr int OFF_Z2H = 114688;             // z2 planes [16][264]u16           8448
constexpr int OFF_Z2L = 114688 + 8448;      //                                  8448
constexpr int OFF_HBH = OFF_Z2H;            // ALIAS: h planes [16][136]u16 (dead when z2 live)
constexpr int OFF_HBL = OFF_Z2H + 4352;
constexpr int OFF_U   = 131584;             // union region                    16896
constexpr int OFF_Z1H = OFF_U;              // z1 planes [16][264]u16 ([A]->[B])
constexpr int OFF_Z1L = OFF_U + 8448;
constexpr int OFF_DT  = OFF_U;              // Dt [16][84]f32 ([C]->[D])        5376
constexpr int OFF_OMS = OFF_U + 5376;       // oms [16][68]f32                  4352
constexpr int OFF_RED = OFF_U + 5376+4352;  // red [16][8]f32                    512
constexpr int OFF_HB  = 131584 + 16896;     // hb f32 [16][128] persistent      8192
constexpr size_t LDS_BYTES = 156672;        // <= 160 KiB
}

typedef __attribute__((ext_vector_type(8))) short short8;
typedef __attribute__((ext_vector_type(4))) float f32x4;

__device__ __forceinline__ float softplusf(float x) {
  return fmaxf(x, 0.0f) + log1pf(expf(-fabsf(x)));
}
__device__ __forceinline__ unsigned short f2bf(float x) {
  unsigned u = __float_as_uint(x);
  return (unsigned short)((u + 0x7FFFu + ((u >> 16) & 1u)) >> 16);
}
__device__ __forceinline__ float bf2f(unsigned short h) {
  return __uint_as_float(((unsigned)h) << 16);
}
#define ALOAD32(p)    __hip_atomic_load((p),  __ATOMIC_RELAXED, __HIP_MEMORY_SCOPE_AGENT)
#define ASTORE32(p,v) __hip_atomic_store((p), (v), __ATOMIC_RELAXED, __HIP_MEMORY_SCOPE_AGENT)
#define ALOAD64(p)    __hip_atomic_load((p),  __ATOMIC_RELAXED, __HIP_MEMORY_SCOPE_AGENT)
#define ASTORE64(p,v) __hip_atomic_store((p), (v), __ATOMIC_RELAXED, __HIP_MEMORY_SCOPE_AGENT)

__device__ __forceinline__ void pack8(const float* v, short8& hi, short8& lo) {
#pragma unroll
  for (int e = 0; e < 8; ++e) {
    unsigned short hh = f2bf(v[e]);
    hi[e] = (short)hh;
    lo[e] = (short)f2bf(v[e] - bf2f(hh));
  }
}

__global__ void __launch_bounds__(256)
rde_init(const float* __restrict__ x0,
         const float* __restrict__ iw1, const float* __restrict__ ib1,
         const float* __restrict__ iw2, const float* __restrict__ ib2,
         const float* __restrict__ iw3, const float* __restrict__ ib3,
         float* __restrict__ hist) {
  __shared__ float xs[kIN];
  __shared__ __align__(16) float t1[kH];
  __shared__ __align__(16) float t2[kH];
  const int b = blockIdx.x, tid = threadIdx.x;
  if (tid < kIN) xs[tid] = x0[b*kIN + tid];
  __syncthreads();
  {
    float a = ib1[tid];
#pragma unroll
    for (int i = 0; i < kIN; ++i) a = fmaf(xs[i], iw1[tid*kIN + i], a);
    t1[tid] = softplusf(a);
  }
  __syncthreads();
  {
    const float4* wr = (const float4*)(iw2 + (size_t)tid*kH);
    float a = ib2[tid];
#pragma unroll 8
    for (int q = 0; q < kH/4; ++q) {
      float4 w = wr[q];
      a = fmaf(t1[4*q+0], w.x, a); a = fmaf(t1[4*q+1], w.y, a);
      a = fmaf(t1[4*q+2], w.z, a); a = fmaf(t1[4*q+3], w.w, a);
    }
    t2[tid] = softplusf(a);
  }
  __syncthreads();
  if (tid < kD) {
    const float4* wr = (const float4*)(iw3 + (size_t)tid*kH);
    float a = ib3[tid];
#pragma unroll 8
    for (int q = 0; q < kH/4; ++q) {
      float4 w = wr[q];
      a = fmaf(t2[4*q+0], w.x, a); a = fmaf(t2[4*q+1], w.y, a);
      a = fmaf(t2[4*q+2], w.z, a); a = fmaf(t2[4*q+3], w.w, a);
    }
    hist[(size_t)b*kD + tid] = a;
  }
}

__global__ void __launch_bounds__(NTHR, 1)
rde_scan(const float* __restrict__ lsg,
         const float* __restrict__ fw1, const float* __restrict__ fb1,
         const float* __restrict__ fw2, const float* __restrict__ fb2,
         const float* __restrict__ fw3, const float* __restrict__ fb3,
         float* __restrict__ hist,
         unsigned* z2x, unsigned* z2snt, unsigned long long* partx) {
  extern __shared__ char smem[];
  unsigned short* W3L  = (unsigned short*)(smem + OFF_W3L);
  unsigned short* W2F  = (unsigned short*)(smem + OFF_W2F);
  unsigned short* z2hi = (unsigned short*)(smem + OFF_Z2H);
  unsigned short* z2lo = (unsigned short*)(smem + OFF_Z2L);
  unsigned short* hbh  = (unsigned short*)(smem + OFF_HBH);  // alias of z2 region
  unsigned short* hbl  = (unsigned short*)(smem + OFF_HBL);
  unsigned short* z1hi = (unsigned short*)(smem + OFF_Z1H);  // alias of U region
  unsigned short* z1lo = (unsigned short*)(smem + OFF_Z1L);
  float* Dt   = (float*)(smem + OFF_DT);                     // alias of U region
  float* oms  = (float*)(smem + OFF_OMS);
  float* red  = (float*)(smem + OFF_RED);
  float* hb   = (float*)(smem + OFF_HB);

  const int tid  = threadIdx.x;
  const int k    = blockIdx.x;
  const int wave = tid >> 6, lane = tid & 63;
  const int l15  = lane & 15, g = lane >> 4;
  const int d_own = k >> 1, l0 = (k & 1) * LH;
  const bool isMLP = (k < NMLP);
  const int j0 = k * 32;                      // z2 column eighth (valid if isMLP)

  // ---------------- prologue ----------------
  // fw3 slice -> LDS fragment order (hi/lo bf16) — all blocks
  for (int i = tid; i < NTILE*8*64; i += NTHR) {
    const int w = i >> 9, s = (i >> 6) & 7, ln = i & 63;
    const int nl = w*16 + (ln & 15), gg = ln >> 4;
    float v[8];
    if (nl < LH) {
      const float* wrow = fw3 + ((size_t)d_own*kL + l0 + nl)*kH + s*32 + gg*8;
      float4 a0 = *(const float4*)(wrow), a1 = *(const float4*)(wrow + 4);
      v[0]=a0.x; v[1]=a0.y; v[2]=a0.z; v[3]=a0.w;
      v[4]=a1.x; v[5]=a1.y; v[6]=a1.z; v[7]=a1.w;
    } else {
#pragma unroll
      for (int e = 0; e < 8; ++e) v[e] = 0.f;
    }
    short8 hi, lo; pack8(v, hi, lo);
    *(short8*)(W3L + (((w*8+s)*2+0)*64 + ln)*8) = hi;
    *(short8*)(W3L + (((w*8+s)*2+1)*64 + ln)*8) = lo;
  }
  float biasv = 0.f;
  if (wave < NTILE) {
    int nl = wave*16 + l15;
    if (nl < LH) biasv = fb3[(size_t)d_own*kL + l0 + nl];
  }

  // MLP prologue: fw1 frags -> VGPR (64/wave), fw2 eighth -> LDS frags, h0
  short8 bw1h[2][4], bw1l[2][4];
  float fb1v[2] = {0.f, 0.f}, fb2v = 0.f;
  if (isMLP) {
#pragma unroll
    for (int ti = 0; ti < 2; ++ti) {
      const int n = (wave*2 + ti)*16 + l15;
      fb1v[ti] = fb1[n];
#pragma unroll
      for (int kst = 0; kst < 4; ++kst) {
        const float* p = fw1 + (size_t)n*kD + kst*32 + g*8;
        float v[8];
        float4 a0 = *(const float4*)p, a1 = *(const float4*)(p + 4);
        v[0]=a0.x; v[1]=a0.y; v[2]=a0.z; v[3]=a0.w;
        v[4]=a1.x; v[5]=a1.y; v[6]=a1.z; v[7]=a1.w;
        pack8(v, bw1h[ti][kst], bw1l[ti][kst]);
      }
    }
    if (wave < 2) fb2v = fb2[j0 + wave*16 + l15];
    // fw2 eighth -> LDS fragments: [2 nt][8 kst][2 pl][64][8]
    for (int i = tid; i < 2*8*64; i += NTHR) {
      const int nt = i >> 9, s = (i >> 6) & 7, ln = i & 63;
      const int n = j0 + nt*16 + (ln & 15);
      const float* p = fw2 + (size_t)n*kH + s*32 + (ln >> 4)*8;
      float v[8];
      float4 a0 = *(const float4*)p, a1 = *(const float4*)(p + 4);
      v[0]=a0.x; v[1]=a0.y; v[2]=a0.z; v[3]=a0.w;
      v[4]=a1.x; v[5]=a1.y; v[6]=a1.z; v[7]=a1.w;
      short8 hi, lo; pack8(v, hi, lo);
      *(short8*)(W2F + (((nt*8+s)*2+0)*64 + ln)*8) = hi;
      *(short8*)(W2F + (((nt*8+s)*2+1)*64 + ln)*8) = lo;
    }
    // h0: hist[0] -> hb (f32) + hbh/hbl planes
    {
      int idx = tid*4, b = idx >> 7, d = idx & 127;
      float4 h4 = *(const float4*)(hist + (size_t)b*kD + d);
      *(float4*)(hb + b*kD + d) = h4;
      float hv[4] = {h4.x, h4.y, h4.z, h4.w};
      unsigned short hh[4], ll[4];
#pragma unroll
      for (int i = 0; i < 4; ++i) { hh[i] = f2bf(hv[i]); ll[i] = f2bf(hv[i] - bf2f(hh[i])); }
      *(unsigned*)(hbh + b*136 + d)     = (unsigned)hh[0] | ((unsigned)hh[1] << 16);
      *(unsigned*)(hbh + b*136 + d + 2) = (unsigned)hh[2] | ((unsigned)hh[3] << 16);
      *(unsigned*)(hbl + b*136 + d)     = (unsigned)ll[0] | ((unsigned)ll[1] << 16);
      *(unsigned*)(hbl + b*136 + d + 2) = (unsigned)ll[2] | ((unsigned)ll[3] << 16);
    }
  }
  __syncthreads();

  // ---------------- scan ----------------
  for (int t = 0; t < kSteps; ++t) {
    const unsigned epw = (unsigned)(t + 1);

    if (isMLP) {
      // [A] z1 = softplus(h @ fw1^T): all 8 waves, 2 n-tiles each, K=128
      {
        f32x4 a0 = {fb1v[0], fb1v[0], fb1v[0], fb1v[0]};
        f32x4 a1 = {fb1v[1], fb1v[1], fb1v[1], fb1v[1]};
#pragma unroll
        for (int kst = 0; kst < 4; ++kst) {
          short8 ah = *(const short8*)(hbh + l15*136 + kst*32 + g*8);
          short8 al = *(const short8*)(hbl + l15*136 + kst*32 + g*8);
          a0 = __builtin_amdgcn_mfma_f32_16x16x32_bf16(ah, bw1h[0][kst], a0, 0, 0, 0);
          a0 = __builtin_amdgcn_mfma_f32_16x16x32_bf16(ah, bw1l[0][kst], a0, 0, 0, 0);
          a0 = __builtin_amdgcn_mfma_f32_16x16x32_bf16(al, bw1h[0][kst], a0, 0, 0, 0);
          a1 = __builtin_amdgcn_mfma_f32_16x16x32_bf16(ah, bw1h[1][kst], a1, 0, 0, 0);
          a1 = __builtin_amdgcn_mfma_f32_16x16x32_bf16(ah, bw1l[1][kst], a1, 0, 0, 0);
          a1 = __builtin_amdgcn_mfma_f32_16x16x32_bf16(al, bw1h[1][kst], a1, 0, 0, 0);
        }
#pragma unroll
        for (int r = 0; r < 4; ++r) {
          const int row = g*4 + r;
          float v0 = softplusf(a0[r]);
          float v1 = softplusf(a1[r]);
          unsigned short h0 = f2bf(v0), h1 = f2bf(v1);
          z1hi[row*264 + (wave*2+0)*16 + l15] = h0;
          z1lo[row*264 + (wave*2+0)*16 + l15] = f2bf(v0 - bf2f(h0));
          z1hi[row*264 + (wave*2+1)*16 + l15] = h1;
          z1lo[row*264 + (wave*2+1)*16 + l15] = f2bf(v1 - bf2f(h1));
        }
      }
      __syncthreads();
      // [B] z2 eighth: waves 0-1, one n-tile each, K=256, B-frags from LDS
      if (wave < 2) {
        const int nt = wave;
        f32x4 acc = {fb2v, fb2v, fb2v, fb2v};
#pragma unroll
        for (int s = 0; s < 8; ++s) {
          short8 ah = *(const short8*)(z1hi + l15*264 + s*32 + g*8);
          short8 al = *(const short8*)(z1lo + l15*264 + s*32 + g*8);
          short8 bh = *(const short8*)(W2F + (((nt*8+s)*2+0)*64 + lane)*8);
          short8 bl = *(const short8*)(W2F + (((nt*8+s)*2+1)*64 + lane)*8);
          acc = __builtin_amdgcn_mfma_f32_16x16x32_bf16(ah, bh, acc, 0, 0, 0);
          acc = __builtin_amdgcn_mfma_f32_16x16x32_bf16(ah, bl, acc, 0, 0, 0);
          acc = __builtin_amdgcn_mfma_f32_16x16x32_bf16(al, bh, acc, 0, 0, 0);
        }
#pragma unroll
        for (int r = 0; r < 4; ++r) {
          float v = softplusf(acc[r]);
          unsigned short hh = f2bf(v), ll = f2bf(v - bf2f(hh));
          ASTORE32(z2x + (g*4 + r)*kH + j0 + nt*16 + l15,
                   (unsigned)hh | ((unsigned)ll << 16));
        }
      }
      __syncthreads();                 // drains z2x stores (vmcnt) in all waves
      if (tid == 0) ASTORE32(z2snt + k*32, epw);
    }

    // ---- all blocks: poll 8 sentinels (tiny traffic), then bulk-read z2 ----
    if (tid < NMLP) {
      while (ALOAD32(z2snt + tid*32) != epw) __builtin_amdgcn_s_sleep(1);
    }
    __syncthreads();
    asm volatile("" ::: "memory");
    {
      unsigned pk[8];
      const unsigned* src = z2x + tid*8;
#pragma unroll
      for (int i = 0; i < 8; ++i) pk[i] = ALOAD32(src + i);
      const int e0 = tid*8, m = e0 >> 8, kk = e0 & 255;
      unsigned short* ph = z2hi + m*264 + kk;
      unsigned short* pl = z2lo + m*264 + kk;
#pragma unroll
      for (int i = 0; i < 4; ++i) {
        unsigned a = pk[2*i], b = pk[2*i+1];
        *(unsigned*)(ph + 2*i) = (a & 0xffffu) | (b << 16);
        *(unsigned*)(pl + 2*i) = (a >> 16) | (b & 0xffff0000u);
      }
    }
    __syncthreads();

    // [C] z3: waves 0-4 MFMA; waves 5-7 load lsg slice -> oms
    if (wave < NTILE) {
      f32x4 acc = {biasv, biasv, biasv, biasv};
#pragma unroll
      for (int s = 0; s < 8; ++s) {
        short8 ah = *(const short8*)(z2hi + l15*264 + s*32 + g*8);
        short8 al = *(const short8*)(z2lo + l15*264 + s*32 + g*8);
        short8 bh = *(const short8*)(W3L + ((wave*16 + s*2 + 0)*64 + lane)*8);
        short8 bl = *(const short8*)(W3L + ((wave*16 + s*2 + 1)*64 + lane)*8);
        acc = __builtin_amdgcn_mfma_f32_16x16x32_bf16(ah, bh, acc, 0, 0, 0);
        acc = __builtin_amdgcn_mfma_f32_16x16x32_bf16(ah, bl, acc, 0, 0, 0);
        acc = __builtin_amdgcn_mfma_f32_16x16x32_bf16(al, bh, acc, 0, 0, 0);
      }
#pragma unroll
      for (int r = 0; r < 4; ++r)
        Dt[(g*4 + r)*84 + wave*16 + l15] = acc[r];
    } else {
#pragma unroll 2
      for (int it = 0; it < 2; ++it) {
        int idx = (wave - 5)*64 + lane + it*192;
        if (idx < 272) {
          int bb = idx / 17, ii = idx % 17;
          float4 v = *(const float4*)(lsg + ((size_t)bb*kSteps + t)*kL + l0 + ii*4);
          *(float4*)(oms + bb*LH + ii*4) = v;
        }
      }
    }
    __syncthreads();

    // [D] contraction -> per-b partial, publish epoch-packed u64
    {
      const int b3 = tid & 15, lb = tid >> 4;
      float p = tanhf(Dt[b3*84 + lb     ]) * oms[b3*LH + lb     ]
              + tanhf(Dt[b3*84 + lb + 32]) * oms[b3*LH + lb + 32];
      if (lb < 4)
        p += tanhf(Dt[b3*84 + lb + 64]) * oms[b3*LH + lb + 64];
      p += __shfl_xor(p, 16); p += __shfl_xor(p, 32);
      if (lane < 16) red[lane*8 + wave] = p;
    }
    __syncthreads();
    if (tid < 16) {
      float s = 0.f;
#pragma unroll
      for (int jw = 0; jw < 8; ++jw) s += red[tid*8 + jw];
      unsigned long long pk = (unsigned long long)__float_as_uint(s)
                            | ((unsigned long long)epw << 32);
      ASTORE64(partx + (size_t)tid*NBLK + k, pk);   // partx[b][k]
    }

    // [E] MLP blocks: poll ALL 4096 partials, update replicated h, repack
    if (isMLP) {
      const unsigned long long* src = partx + (size_t)tid*8;
      unsigned long long q8[8];
      for (;;) {
        bool ok = true;
#pragma unroll
        for (int i = 0; i < 8; ++i) q8[i] = ALOAD64(src + i);
#pragma unroll
        for (int i = 0; i < 8; ++i) ok &= ((unsigned)(q8[i] >> 32) == epw);
        if (ok) break;
        __builtin_amdgcn_s_sleep(1);
      }
      {
        const int b = tid >> 5, ks0 = (tid & 31)*8;
#pragma unroll
        for (int i = 0; i < 4; ++i) {
          float p0 = __uint_as_float((unsigned)q8[2*i]);
          float p1 = __uint_as_float((unsigned)q8[2*i+1]);
          hb[b*kD + (ks0 >> 1) + i] += p0 + p1;
        }
      }
      __syncthreads();
      {
        int idx = tid*4, b = idx >> 7, d = idx & 127;
        float4 h4 = *(const float4*)(hb + b*kD + d);
        if (k == 0)
          *(float4*)(hist + ((size_t)(t+1)*kB + b)*kD + d) = h4;
        float hv[4] = {h4.x, h4.y, h4.z, h4.w};
        unsigned short hh[4], ll[4];
#pragma unroll
        for (int i = 0; i < 4; ++i) { hh[i] = f2bf(hv[i]); ll[i] = f2bf(hv[i] - bf2f(hh[i])); }
        *(unsigned*)(hbh + b*136 + d)     = (unsigned)hh[0] | ((unsigned)hh[1] << 16);
        *(unsigned*)(hbh + b*136 + d + 2) = (unsigned)hh[2] | ((unsigned)hh[3] << 16);
        *(unsigned*)(hbl + b*136 + d)     = (unsigned)ll[0] | ((unsigned)ll[1] << 16);
        *(unsigned*)(hbl + b*136 + d + 2) = (unsigned)ll[2] | ((unsigned)ll[3] << 16);
      }
      __syncthreads();
    }
  }
}

__global__ void __launch_bounds__(512)
rde_readout(const float* __restrict__ hist, const float* __restrict__ rw,
            const float* __restrict__ rb, float* __restrict__ out) {
  const int t = blockIdx.x, tid = threadIdx.x;
  const int b = tid >> 5, o = tid & 31;
  const float4* hr = (const float4*)(hist + ((size_t)t*kB + b)*kD);
  const float4* wr = (const float4*)(rw + (size_t)o*kD);
  float a = rb[o];
#pragma unroll 8
  for (int q = 0; q < kD/4; ++q) {
    float4 h4 = hr[q], w4 = wr[q];
    a = fmaf(h4.x,w4.x,a); a = fmaf(h4.y,w4.y,a);
    a = fmaf(h4.z,w4.z,a); a = fmaf(h4.w,w4.w,a);
  }
  out[((size_t)b*kT + t)*kO + o] = a;
}

extern "C" void kernel_launch(void* const* d_in, const int* in_sizes, int n_in,
                              void* d_out, int out_size, void* d_ws, size_t ws_size,
                              hipStream_t stream) {
  const float* x0  = (const float*)d_in[0];
  const float* lsg = (const float*)d_in[1];
  const float* iw1 = (const float*)d_in[2];
  const float* ib1 = (const float*)d_in[3];
  const float* iw2 = (const float*)d_in[4];
  const float* ib2 = (const float*)d_in[5];
  const float* iw3 = (const float*)d_in[6];
  const float* ib3 = (const float*)d_in[7];
  const float* fw1 = (const float*)d_in[8];
  const float* fb1 = (const float*)d_in[9];
  const float* fw2 = (const float*)d_in[10];
  const float* fb2 = (const float*)d_in[11];
  const float* fw3 = (const float*)d_in[12];
  const float* fb3 = (const float*)d_in[13];
  const float* rw  = (const float*)d_in[14];
  const float* rb  = (const float*)d_in[15];
  float* out = (float*)d_out;

  float* hist = (float*)d_ws;                                 // 512*16*128 f32
  unsigned* z2x   = (unsigned*)(hist + (size_t)kT*kB*kD);     // [16][256] u32
  unsigned* z2snt = z2x + kB*kH;                              // 8*32 u32
  unsigned long long* partx =
      (unsigned long long*)(z2snt + NMLP*32);                 // [16][256] u64

  // zero z2x + sentinels + partx (deterministic epochs each launch)
  hipMemsetAsync(z2x, 0, (size_t)kB*kH*4 + (size_t)NMLP*32*4 + (size_t)kB*NBLK*8,
                 stream);
  hipFuncSetAttribute((const void*)rde_scan,
                      hipFuncAttributeMaxDynamicSharedMemorySize, (int)LDS_BYTES);

  rde_init<<<kB, 256, 0, stream>>>(x0, iw1, ib1, iw2, ib2, iw3, ib3, hist);

  void* args[] = { (void*)&lsg, (void*)&fw1, (void*)&fb1, (void*)&fw2, (void*)&fb2,
                   (void*)&fw3, (void*)&fb3, (void*)&hist, (void*)&z2x,
                   (void*)&z2snt, (void*)&partx };
  hipLaunchCooperativeKernel((const void*)rde_scan, dim3(NBLK), dim3(NTHR),
                             args, (unsigned)LDS_BYTES, stream);

  rde_readout<<<kT, 512, 0, stream>>>(hist, rw, rb, out);
}

// Round 8
// 4637.511 us; speedup vs baseline: 1.5094x; 1.5094x over previous
//
#include <hip/hip_runtime.h>

namespace {
constexpr int kB = 16, kT = 512, kIN = 16, kD = 128, kH = 256, kL = 136, kO = 32;
constexpr int kSteps = kT - 1;      // 511
constexpr int NBLK = 256;           // block k: z3 shard d = k>>1, l-half = k&1
constexpr int NTHR = 512;
constexpr int LH   = 68;
constexpr int NTILE = 5;            // z3 MFMA n-tiles (80 cols, 68 real)
constexpr int NMLPB = 128;          // blocks 0..127: MLP role (b = k>>3, eighth = k&7)
// ---- LDS layout (bytes) ----
constexpr int OFF_W3L = 0;          // fw3 frags [5][8][2][64][8]bf16   81920
constexpr int OFF_FW2 = 81920;      // fw2 eighth [128][68] f32         34816
constexpr int OFF_Z2H = 116736;     // z2 planes [16][264] u16           8448
constexpr int OFF_Z2L = 125184;     //                                   8448
constexpr int OFF_DT  = 133632;     // [16][84] f32                      5376
constexpr int OFF_OMS = 139008;     // [16][68] f32                      4352
constexpr int OFF_RED = 143360;     // [16][8]  f32                       512
constexpr int OFF_Z1S = 143872;     // [256] f32                         1024
constexpr int OFF_HB  = 144896;     // [128] f32                          512
constexpr int OFF_HINC= 145408;     // [128] f32                          512
constexpr int OFF_HHI = 145920;     // [128] u16                          256
constexpr int OFF_HLO = 146176;     // [128] u16                          256
constexpr size_t LDS_BYTES = 146432;
}

typedef __attribute__((ext_vector_type(8))) short short8;
typedef __attribute__((ext_vector_type(4))) float f32x4;

__device__ __forceinline__ float softplusf(float x) {
  return fmaxf(x, 0.0f) + log1pf(expf(-fabsf(x)));
}
__device__ __forceinline__ unsigned short f2bf(float x) {
  unsigned u = __float_as_uint(x);
  return (unsigned short)((u + 0x7FFFu + ((u >> 16) & 1u)) >> 16);
}
__device__ __forceinline__ float bf2f(unsigned short h) {
  return __uint_as_float(((unsigned)h) << 16);
}
#define ALOAD32(p)    __hip_atomic_load((p),  __ATOMIC_RELAXED, __HIP_MEMORY_SCOPE_AGENT)
#define ASTORE32(p,v) __hip_atomic_store((p), (v), __ATOMIC_RELAXED, __HIP_MEMORY_SCOPE_AGENT)
#define ALOAD64(p)    __hip_atomic_load((p),  __ATOMIC_RELAXED, __HIP_MEMORY_SCOPE_AGENT)
#define ASTORE64(p,v) __hip_atomic_store((p), (v), __ATOMIC_RELAXED, __HIP_MEMORY_SCOPE_AGENT)

__device__ __forceinline__ void pack8(const float* v, short8& hi, short8& lo) {
#pragma unroll
  for (int e = 0; e < 8; ++e) {
    unsigned short hh = f2bf(v[e]);
    hi[e] = (short)hh;
    lo[e] = (short)f2bf(v[e] - bf2f(hh));
  }
}

__global__ void __launch_bounds__(256)
rde_init(const float* __restrict__ x0,
         const float* __restrict__ iw1, const float* __restrict__ ib1,
         const float* __restrict__ iw2, const float* __restrict__ ib2,
         const float* __restrict__ iw3, const float* __restrict__ ib3,
         float* __restrict__ hist) {
  __shared__ float xs[kIN];
  __shared__ __align__(16) float t1[kH];
  __shared__ __align__(16) float t2[kH];
  const int b = blockIdx.x, tid = threadIdx.x;
  if (tid < kIN) xs[tid] = x0[b*kIN + tid];
  __syncthreads();
  {
    float a = ib1[tid];
#pragma unroll
    for (int i = 0; i < kIN; ++i) a = fmaf(xs[i], iw1[tid*kIN + i], a);
    t1[tid] = softplusf(a);
  }
  __syncthreads();
  {
    const float4* wr = (const float4*)(iw2 + (size_t)tid*kH);
    float a = ib2[tid];
#pragma unroll 8
    for (int q = 0; q < kH/4; ++q) {
      float4 w = wr[q];
      a = fmaf(t1[4*q+0], w.x, a); a = fmaf(t1[4*q+1], w.y, a);
      a = fmaf(t1[4*q+2], w.z, a); a = fmaf(t1[4*q+3], w.w, a);
    }
    t2[tid] = softplusf(a);
  }
  __syncthreads();
  if (tid < kD) {
    const float4* wr = (const float4*)(iw3 + (size_t)tid*kH);
    float a = ib3[tid];
#pragma unroll 8
    for (int q = 0; q < kH/4; ++q) {
      float4 w = wr[q];
      a = fmaf(t2[4*q+0], w.x, a); a = fmaf(t2[4*q+1], w.y, a);
      a = fmaf(t2[4*q+2], w.z, a); a = fmaf(t2[4*q+3], w.w, a);
    }
    hist[(size_t)b*kD + tid] = a;
  }
}

__global__ void __launch_bounds__(NTHR, 1)
rde_scan(const float* __restrict__ lsg,
         const float* __restrict__ fw1, const float* __restrict__ fb1,
         const float* __restrict__ fw2, const float* __restrict__ fb2,
         const float* __restrict__ fw3, const float* __restrict__ fb3,
         float* __restrict__ hist,
         unsigned* z2x, unsigned* z2snt, unsigned long long* partx) {
  extern __shared__ char smem[];
  unsigned short* W3L  = (unsigned short*)(smem + OFF_W3L);
  float* fw2s = (float*)(smem + OFF_FW2);                    // [128][68] pair-major
  unsigned short* z2hi = (unsigned short*)(smem + OFF_Z2H);
  unsigned short* z2lo = (unsigned short*)(smem + OFF_Z2L);
  float* Dt   = (float*)(smem + OFF_DT);
  float* oms  = (float*)(smem + OFF_OMS);
  float* red  = (float*)(smem + OFF_RED);
  float* z1s  = (float*)(smem + OFF_Z1S);
  float* hb   = (float*)(smem + OFF_HB);
  float* hinc = (float*)(smem + OFF_HINC);
  unsigned short* hhi = (unsigned short*)(smem + OFF_HHI);
  unsigned short* hlo = (unsigned short*)(smem + OFF_HLO);

  const int tid  = threadIdx.x;
  const int k    = blockIdx.x;
  const int wave = tid >> 6, lane = tid & 63;
  const int l15  = lane & 15, g = lane >> 4;
  const int d_own = k >> 1, l0 = (k & 1) * LH;               // z3 shard
  const bool isMLP = (k < NMLPB);
  const int b_own = k >> 3, e8 = k & 7, j0 = e8 * 32;        // MLP role

  // ---------------- prologue ----------------
  // fw3 shard -> LDS fragment order (hi/lo bf16) — all blocks
  for (int i = tid; i < NTILE*8*64; i += NTHR) {
    const int w = i >> 9, s = (i >> 6) & 7, ln = i & 63;
    const int nl = w*16 + (ln & 15), gg = ln >> 4;
    float v[8];
    if (nl < LH) {
      const float* wrow = fw3 + ((size_t)d_own*kL + l0 + nl)*kH + s*32 + gg*8;
      float4 a0 = *(const float4*)(wrow), a1 = *(const float4*)(wrow + 4);
      v[0]=a0.x; v[1]=a0.y; v[2]=a0.z; v[3]=a0.w;
      v[4]=a1.x; v[5]=a1.y; v[6]=a1.z; v[7]=a1.w;
    } else {
#pragma unroll
      for (int e = 0; e < 8; ++e) v[e] = 0.f;
    }
    short8 hi, lo; pack8(v, hi, lo);
    *(short8*)(W3L + (((w*8+s)*2+0)*64 + ln)*8) = hi;
    *(short8*)(W3L + (((w*8+s)*2+1)*64 + ln)*8) = lo;
  }
  float biasv = 0.f;
  if (wave < NTILE) {
    int nl = wave*16 + l15;
    if (nl < LH) biasv = fb3[(size_t)d_own*kL + l0 + nl];
  }

  // MLP prologue
  short8 bw1h[2][4], bw1l[2][4];
  float fb1v[2] = {0.f, 0.f}, fb2v = 0.f;
  if (isMLP) {
#pragma unroll
    for (int ti = 0; ti < 2; ++ti) {
      const int n = (wave*2 + ti)*16 + l15;
      fb1v[ti] = fb1[n];
#pragma unroll
      for (int kst = 0; kst < 4; ++kst) {
        const float* p = fw1 + (size_t)n*kD + kst*32 + g*8;
        float v[8];
        float4 a0 = *(const float4*)p, a1 = *(const float4*)(p + 4);
        v[0]=a0.x; v[1]=a0.y; v[2]=a0.z; v[3]=a0.w;
        v[4]=a1.x; v[5]=a1.y; v[6]=a1.z; v[7]=a1.w;
        pack8(v, bw1h[ti][kst], bw1l[ti][kst]);
      }
    }
    fb2v = fb2[j0 + (tid >> 4)];
    // fw2 eighth -> LDS pair-major: fw2s[kh][2*jl + p], K = 2*kh + p
    for (int i = tid; i < 32*64; i += NTHR) {
      int jl = i >> 6, q = i & 63;
      float4 v = *(const float4*)(fw2 + (size_t)(j0 + jl)*kH + q*4);
      fw2s[(2*q  )*68 + 2*jl    ] = v.x;
      fw2s[(2*q  )*68 + 2*jl + 1] = v.y;
      fw2s[(2*q+1)*68 + 2*jl    ] = v.z;
      fw2s[(2*q+1)*68 + 2*jl + 1] = v.w;
    }
    // h0 -> hb + hi/lo planes
    if (tid < kD) {
      float hv = hist[(size_t)b_own*kD + tid];
      hb[tid] = hv;
      unsigned short hh = f2bf(hv);
      hhi[tid] = hh; hlo[tid] = f2bf(hv - bf2f(hh));
    }
  }
  __syncthreads();

  // ---------------- scan ----------------
  for (int t = 0; t < kSteps; ++t) {
    const unsigned epw = (unsigned)(t + 1);

    if (isMLP) {
      // [A] z1 full (own b) via MFMA, fw1 frags in VGPR; A = broadcast h planes
      {
        f32x4 a0 = {fb1v[0], fb1v[0], fb1v[0], fb1v[0]};
        f32x4 a1 = {fb1v[1], fb1v[1], fb1v[1], fb1v[1]};
#pragma unroll
        for (int kst = 0; kst < 4; ++kst) {
          short8 ah = *(const short8*)(hhi + kst*32 + g*8);
          short8 al = *(const short8*)(hlo + kst*32 + g*8);
          a0 = __builtin_amdgcn_mfma_f32_16x16x32_bf16(ah, bw1h[0][kst], a0, 0, 0, 0);
          a0 = __builtin_amdgcn_mfma_f32_16x16x32_bf16(ah, bw1l[0][kst], a0, 0, 0, 0);
          a0 = __builtin_amdgcn_mfma_f32_16x16x32_bf16(al, bw1h[0][kst], a0, 0, 0, 0);
          a1 = __builtin_amdgcn_mfma_f32_16x16x32_bf16(ah, bw1h[1][kst], a1, 0, 0, 0);
          a1 = __builtin_amdgcn_mfma_f32_16x16x32_bf16(ah, bw1l[1][kst], a1, 0, 0, 0);
          a1 = __builtin_amdgcn_mfma_f32_16x16x32_bf16(al, bw1h[1][kst], a1, 0, 0, 0);
        }
        if (g == 0) {                       // row 0 of C = our h row
          z1s[(wave*2+0)*16 + l15] = softplusf(a0[0]);
          z1s[(wave*2+1)*16 + l15] = softplusf(a1[0]);
        }
      }
      __syncthreads();
      // [B] z2 eighth (own b) via f32 VALU; publish packed hi/lo + sentinel
      {
        const int jl = tid >> 4, ks = tid & 15;
        float a = 0.f;
#pragma unroll
        for (int kh = ks; kh < 128; kh += 16) {
          float2 z2v = *(const float2*)(z1s + 2*kh);
          a = fmaf(z2v.x, fw2s[kh*68 + 2*jl    ], a);
          a = fmaf(z2v.y, fw2s[kh*68 + 2*jl + 1], a);
        }
        a += __shfl_xor(a, 1); a += __shfl_xor(a, 2);
        a += __shfl_xor(a, 4); a += __shfl_xor(a, 8);
        if (ks == 0) {
          float v = softplusf(a + fb2v);
          unsigned short hh = f2bf(v), ll = f2bf(v - bf2f(hh));
          ASTORE32(z2x + b_own*kH + j0 + jl, (unsigned)hh | ((unsigned)ll << 16));
        }
      }
      __syncthreads();                      // drains z2x stores in all waves
      if (tid == 0) ASTORE32(z2snt + k*32, epw);
    }

    // ---- all blocks: poll 128 sentinels (1 thread/line), bulk-read z2 ----
    if (tid < NMLPB) {
      while (ALOAD32(z2snt + tid*32) != epw) __builtin_amdgcn_s_sleep(1);
    }
    __syncthreads();
    asm volatile("" ::: "memory");
    {
      unsigned pk[8];
      const unsigned* src = z2x + tid*8;
#pragma unroll
      for (int i = 0; i < 8; ++i) pk[i] = ALOAD32(src + i);
      const int e0 = tid*8, m = e0 >> 8, kk = e0 & 255;
      unsigned short* ph = z2hi + m*264 + kk;
      unsigned short* pl = z2lo + m*264 + kk;
#pragma unroll
      for (int i = 0; i < 4; ++i) {
        unsigned a = pk[2*i], b = pk[2*i+1];
        *(unsigned*)(ph + 2*i) = (a & 0xffffu) | (b << 16);
        *(unsigned*)(pl + 2*i) = (a >> 16) | (b & 0xffff0000u);
      }
    }
    __syncthreads();

    // [C] z3: waves 0-4 MFMA; waves 5-7 load lsg slice -> oms
    if (wave < NTILE) {
      f32x4 acc = {biasv, biasv, biasv, biasv};
#pragma unroll
      for (int s = 0; s < 8; ++s) {
        short8 ah = *(const short8*)(z2hi + l15*264 + s*32 + g*8);
        short8 al = *(const short8*)(z2lo + l15*264 + s*32 + g*8);
        short8 bh = *(const short8*)(W3L + ((wave*16 + s*2 + 0)*64 + lane)*8);
        short8 bl = *(const short8*)(W3L + ((wave*16 + s*2 + 1)*64 + lane)*8);
        acc = __builtin_amdgcn_mfma_f32_16x16x32_bf16(ah, bh, acc, 0, 0, 0);
        acc = __builtin_amdgcn_mfma_f32_16x16x32_bf16(ah, bl, acc, 0, 0, 0);
        acc = __builtin_amdgcn_mfma_f32_16x16x32_bf16(al, bh, acc, 0, 0, 0);
      }
#pragma unroll
      for (int r = 0; r < 4; ++r)
        Dt[(g*4 + r)*84 + wave*16 + l15] = acc[r];
    } else {
#pragma unroll 2
      for (int it = 0; it < 2; ++it) {
        int idx = (wave - 5)*64 + lane + it*192;
        if (idx < 272) {
          int bb = idx / 17, ii = idx % 17;
          float4 v = *(const float4*)(lsg + ((size_t)bb*kSteps + t)*kL + l0 + ii*4);
          *(float4*)(oms + bb*LH + ii*4) = v;
        }
      }
    }
    __syncthreads();

    // [D] contraction -> per-b partial, publish epoch-packed u64
    {
      const int b3 = tid & 15, lb = tid >> 4;
      float p = tanhf(Dt[b3*84 + lb     ]) * oms[b3*LH + lb     ]
              + tanhf(Dt[b3*84 + lb + 32]) * oms[b3*LH + lb + 32];
      if (lb < 4)
        p += tanhf(Dt[b3*84 + lb + 64]) * oms[b3*LH + lb + 64];
      p += __shfl_xor(p, 16); p += __shfl_xor(p, 32);
      if (lane < 16) red[lane*8 + wave] = p;
    }
    __syncthreads();
    if (tid < 16) {
      float s = 0.f;
#pragma unroll
      for (int jw = 0; jw < 8; ++jw) s += red[tid*8 + jw];
      unsigned long long pk = (unsigned long long)__float_as_uint(s)
                            | ((unsigned long long)epw << 32);
      ASTORE64(partx + (size_t)tid*NBLK + k, pk);   // partx[b][k]
    }

    // [E] MLP blocks: self-throttling per-thread poll of own-b partials, h update
    if (isMLP) {
      if (tid < 256) {
        const unsigned long long* pp = partx + (size_t)b_own*NBLK + tid;
        unsigned long long q;
        for (;;) {
          q = ALOAD64(pp);
          if ((unsigned)(q >> 32) == epw) break;
          __builtin_amdgcn_s_sleep(1);
        }
        float pv = __uint_as_float((unsigned)q);
        float p2 = pv + __shfl_xor(pv, 1);
        if ((tid & 1) == 0) hinc[tid >> 1] = p2;
      }
      __syncthreads();
      if (tid < kD) {
        float hn = hb[tid] + hinc[tid];
        hb[tid] = hn;
        if (e8 == 0) hist[((size_t)(t+1)*kB + b_own)*kD + tid] = hn;
        unsigned short hh = f2bf(hn);
        hhi[tid] = hh; hlo[tid] = f2bf(hn - bf2f(hh));
      }
      __syncthreads();
    }
  }
}

__global__ void __launch_bounds__(512)
rde_readout(const float* __restrict__ hist, const float* __restrict__ rw,
            const float* __restrict__ rb, float* __restrict__ out) {
  const int t = blockIdx.x, tid = threadIdx.x;
  const int b = tid >> 5, o = tid & 31;
  const float4* hr = (const float4*)(hist + ((size_t)t*kB + b)*kD);
  const float4* wr = (const float4*)(rw + (size_t)o*kD);
  float a = rb[o];
#pragma unroll 8
  for (int q = 0; q < kD/4; ++q) {
    float4 h4 = hr[q], w4 = wr[q];
    a = fmaf(h4.x,w4.x,a); a = fmaf(h4.y,w4.y,a);
    a = fmaf(h4.z,w4.z,a); a = fmaf(h4.w,w4.w,a);
  }
  out[((size_t)b*kT + t)*kO + o] = a;
}

extern "C" void kernel_launch(void* const* d_in, const int* in_sizes, int n_in,
                              void* d_out, int out_size, void* d_ws, size_t ws_size,
                              hipStream_t stream) {
  const float* x0  = (const float*)d_in[0];
  const float* lsg = (const float*)d_in[1];
  const float* iw1 = (const float*)d_in[2];
  const float* ib1 = (const float*)d_in[3];
  const float* iw2 = (const float*)d_in[4];
  const float* ib2 = (const float*)d_in[5];
  const float* iw3 = (const float*)d_in[6];
  const float* ib3 = (const float*)d_in[7];
  const float* fw1 = (const float*)d_in[8];
  const float* fb1 = (const float*)d_in[9];
  const float* fw2 = (const float*)d_in[10];
  const float* fb2 = (const float*)d_in[11];
  const float* fw3 = (const float*)d_in[12];
  const float* fb3 = (const float*)d_in[13];
  const float* rw  = (const float*)d_in[14];
  const float* rb  = (const float*)d_in[15];
  float* out = (float*)d_out;

  float* hist = (float*)d_ws;                                 // 512*16*128 f32
  unsigned* z2x   = (unsigned*)(hist + (size_t)kT*kB*kD);     // [16][256] u32
  unsigned* z2snt = z2x + kB*kH;                              // 128*32 u32
  unsigned long long* partx =
      (unsigned long long*)(z2snt + NMLPB*32);                // [16][256] u64

  hipMemsetAsync(z2x, 0,
                 (size_t)kB*kH*4 + (size_t)NMLPB*32*4 + (size_t)kB*NBLK*8, stream);
  hipFuncSetAttribute((const void*)rde_scan,
                      hipFuncAttributeMaxDynamicSharedMemorySize, (int)LDS_BYTES);

  rde_init<<<kB, 256, 0, stream>>>(x0, iw1, ib1, iw2, ib2, iw3, ib3, hist);

  void* args[] = { (void*)&lsg, (void*)&fw1, (void*)&fb1, (void*)&fw2, (void*)&fb2,
                   (void*)&fw3, (void*)&fb3, (void*)&hist, (void*)&z2x,
                   (void*)&z2snt, (void*)&partx };
  hipLaunchCooperativeKernel((const void*)rde_scan, dim3(NBLK), dim3(NTHR),
                             args, (unsigned)LDS_BYTES, stream);

  rde_readout<<<kT, 512, 0, stream>>>(hist, rw, rb, out);
}